// Round 7
// baseline (201.059 us; speedup 1.0000x reference)
//
#include <hip/hip_runtime.h>

// Problem: S=8192, K=1024, O=4096
// out_q[s,o] = clip(round(int8dot(x[s,:], w[o,:]) * sx*sw/sy[s]), -128, 127)
// d_out = [ out_q as float (S*O) | scale_y (S) ]

#define S_DIM 8192
#define K_DIM 1024
#define O_DIM 4096
#define BM 128
#define BN 128
#define BK 64
#define NITER (K_DIM / BK)
#define TILE_BYTES (BM * BK)  // 8192 B tile

using i32x4 = __attribute__((ext_vector_type(4))) int;

__device__ __forceinline__ void load_lds16(const void* g, void* l) {
  __builtin_amdgcn_global_load_lds(
      (const __attribute__((address_space(1))) void*)g,
      (__attribute__((address_space(3))) void*)l, 16, 0, 0);
}

// ---------------- pack: int32 -> int8, two layouts ----------------------------
// A (x): FRAGMENT-LINEAR. Chunk j (16 B) at byte j*16 holds, for
//   t=j>>9 (band=t>>4 of 128 rows, kt=t&15), idx=j&511 (sub=idx>>6, q=(idx>>4)&3,
//   fr=idx&15): row band*128+sub*16+fr, k kt*64+q*16..+15. This is exactly the
//   MFMA A-operand bytes for lane q*16+fr of sub-tile sub — the gemm loads A
//   fragments DIRECTLY from global, 1 KB contiguous per (wave,mi,iter).
// B (w): staging-tile layout with bank swizzle baked in (identical to R6,
//   verified): byte r*64+cs*16 of tile holds chunk (cs^(r&3)) of row band*128+r.
__global__ void pack_kernel(const int* __restrict__ xi, const int* __restrict__ wi,
                            const float* __restrict__ sy,
                            uint4* __restrict__ ap, uint4* __restrict__ bp,
                            float* __restrict__ out_sy) {
  const int tid = blockIdx.x * blockDim.x + threadIdx.x;
  const int nA = S_DIM * K_DIM / 16;  // 512K chunks
  const int nB = O_DIM * K_DIM / 16;  // 256K chunks

  const int4* s4 = nullptr;
  uint4* dst = nullptr;
  int j = 0;
  if (tid < nA) {
    j = tid;
    const int t = j >> 9, idx = j & 511;
    const int sub = idx >> 6, q = (idx >> 4) & 3, fr = idx & 15;
    const int band = t >> 4, kt = t & 15;
    const int row = band * 128 + sub * 16 + fr;
    s4 = (const int4*)xi + row * 256 + kt * 16 + q * 4;
    dst = ap;
  } else if (tid < nA + nB) {
    j = tid - nA;
    const int t = j >> 9, idx = j & 511;
    const int r = idx >> 2, cs = idx & 3, c = cs ^ (r & 3);
    const int band = t >> 4, kt = t & 15;
    const int row = band * 128 + r;
    s4 = (const int4*)wi + row * 256 + kt * 16 + c * 4;
    dst = bp;
  }
  if (s4) {
    int4 v0 = s4[0], v1 = s4[1], v2 = s4[2], v3 = s4[3];
    uint4 o;
    o.x = (v0.x & 0xff) | ((v0.y & 0xff) << 8) | ((v0.z & 0xff) << 16) | (((unsigned)v0.w & 0xff) << 24);
    o.y = (v1.x & 0xff) | ((v1.y & 0xff) << 8) | ((v1.z & 0xff) << 16) | (((unsigned)v1.w & 0xff) << 24);
    o.z = (v2.x & 0xff) | ((v2.y & 0xff) << 8) | ((v2.z & 0xff) << 16) | (((unsigned)v2.w & 0xff) << 24);
    o.w = (v3.x & 0xff) | ((v3.y & 0xff) << 8) | ((v3.z & 0xff) << 16) | (((unsigned)v3.w & 0xff) << 24);
    dst[j] = o;
  }
  if (tid < S_DIM) out_sy[tid] = sy[tid];
}

// ---------------- int8 MFMA GEMM, hybrid flatmm -------------------------------
// A: direct-from-global register fragments, prefetched 1 iter ahead (issued
//    during compute, a full phase in flight before the barrier's vmcnt drain).
// B: LDS dbuf via global_load_lds, one barrier/iter (verified R6 path).
// Removes A's global_load_lds + ds_read latency chain; LDS = 16 KB.
__global__ __launch_bounds__(256, 4) void gemm_i8_kernel(
    const signed char* __restrict__ Ap,  // fragment-linear packed x
    const signed char* __restrict__ Bp,  // tiled-packed w (swizzled)
    const float* __restrict__ sx, const float* __restrict__ sw,
    const float* __restrict__ sy, float* __restrict__ out) {
  __shared__ __align__(16) signed char Bs[2][TILE_BYTES];

  const int tid = threadIdx.x;
  const int wave = tid >> 6;
  const int lane = tid & 63;
  const int wm = wave >> 1;  // 0..1: wave row in block
  const int wn = wave & 1;   // 0..1: wave col in block
  const int rowBase = blockIdx.x * BM;   // x-fast over S keeps B L2-resident
  const int colBase = blockIdx.y * BN;

  // B staging (identical to R6): contiguous 1 KB per instruction.
  const int soff = wave * 1024 + lane * 16;
  const signed char* gB = Bp + (size_t)blockIdx.y * NITER * TILE_BYTES + soff;
  signed char* ldsB = (signed char*)Bs + wave * 1024;

  // A direct-fragment base: + it*8192 + mi*1024 below.
  const signed char* gA = Ap + (size_t)blockIdx.x * NITER * TILE_BYTES +
                          wm * 4096 + lane * 16;

  i32x4 acc[4][4] = {};

  const int fr = lane & 15;                            // fragment row
  const int fq = (((lane >> 4) ^ (fr & 3)) & 3) * 16;  // swizzled chunk slot (B)

  // Prologue: stage B tile 0; load A fragments for iter 0.
  load_lds16(gB, ldsB);
  load_lds16(gB + 4096, ldsB + 4096);
  i32x4 af[2][4];
#pragma unroll
  for (int mi = 0; mi < 4; ++mi)
    af[0][mi] = *(const i32x4*)(gA + mi * 1024);

  for (int it = 0; it < NITER; ++it) {
    const int p = it & 1;
    __syncthreads();  // drains B-stage (and A-prefetch) issued last iter

    if (it + 1 < NITER) {
      // async-stage B tile it+1 + prefetch A frags it+1 (in flight all phase)
      const int boff = ((it + 1) & 1) * TILE_BYTES;
      const size_t goff = (size_t)(it + 1) * TILE_BYTES;
      load_lds16(gB + goff, ldsB + boff);
      load_lds16(gB + goff + 4096, ldsB + boff + 4096);
#pragma unroll
      for (int mi = 0; mi < 4; ++mi)
        af[p ^ 1][mi] = *(const i32x4*)(gA + goff + mi * 1024);
    }

    const signed char* curB = Bs[it & 1];
#pragma unroll
    for (int ni = 0; ni < 4; ++ni) {
      i32x4 bf = *(const i32x4*)(curB + (wn * 64 + ni * 16 + fr) * BK + fq);
#pragma unroll
      for (int mi = 0; mi < 4; ++mi)
        acc[mi][ni] =
            __builtin_amdgcn_mfma_i32_16x16x64_i8(af[p][mi], bf, acc[mi][ni], 0, 0, 0);
    }
  }

  // Epilogue. C/D layout: col = lane&15, row = (lane>>4)*4 + reg.
  const float sxw = sx[0] * sw[0];
  const int quad = lane >> 4;
#pragma unroll
  for (int mi = 0; mi < 4; ++mi) {
#pragma unroll
    for (int r = 0; r < 4; ++r) {
      const int s = rowBase + wm * 64 + mi * 16 + quad * 4 + r;
      const float rs = sxw / sy[s];
      float* orow = out + (size_t)s * O_DIM + colBase + wn * 64 + fr;
#pragma unroll
      for (int ni = 0; ni < 4; ++ni) {
        float f = rintf((float)acc[mi][ni][r] * rs);
        f = fminf(127.0f, fmaxf(-128.0f, f));
        orow[ni * 16] = f;
      }
    }
  }
}

extern "C" void kernel_launch(void* const* d_in, const int* in_sizes, int n_in,
                              void* d_out, int out_size, void* d_ws, size_t ws_size,
                              hipStream_t stream) {
  const int* x = (const int*)d_in[0];        // [S,K] int8 values as int32
  const int* w = (const int*)d_in[1];        // [O,K] int8 values as int32
  const float* sx = (const float*)d_in[2];
  const float* sw = (const float*)d_in[3];
  const float* sy = (const float*)d_in[4];   // [S]
  float* out = (float*)d_out;

  uint4* ap = (uint4*)d_ws;                                   // 8 MB frag-linear A
  uint4* bp = ap + (size_t)S_DIM * K_DIM / 16;                // 4 MB tiled B

  const int total = S_DIM * K_DIM / 16 + O_DIM * K_DIM / 16;  // 768K threads
  pack_kernel<<<(total + 255) / 256, 256, 0, stream>>>(
      x, w, sy, ap, bp, out + (size_t)S_DIM * O_DIM);

  dim3 grid(S_DIM / BM, O_DIM / BN);  // (64, 32), row tiles fast
  gemm_i8_kernel<<<grid, 256, 0, stream>>>(
      (const signed char*)ap, (const signed char*)bp, sx, sw, sy, out);
}